// Round 9
// baseline (118.215 us; speedup 1.0000x reference)
//
#include <hip/hip_runtime.h>

// casConv2d: B=1, C=128, H=W=32, OC=128, K=3, pad=1, stride=1.
// L = 1024, CKK = 1152 = 36 exact 32-tap chunks (reference front-pad chunk == 0).
//
// Round-9: DIAGNOSTIC. Four theories in a row mispredicted; the gemm/fused
// duration split has never been observed (both < the 43us harness fills that
// own top-5). Each kernel body now runs REP=8 times in-dispatch (runtime trip
// count + asm memory clobber defeats CSE; every rep stores identical values,
// so output is bit-identical). Dispatch durations become ~8x per-pass cost ->
// both kernels surface in top-5 WITH counters. R10 reverts to REP=1.
#define L_     1024
#define CKK_   1152
#define QMAX_  255.0f
#define NCH    36
#define PSTR_  (131072 + 64)  // plane stride in floats (R8 pad kept)

// grid = (16 l-tiles of 64 px, 36 chunks) = 576 blocks, 256 threads.
__global__ __launch_bounds__(256) void gemm_chunks(
    const float* __restrict__ x,      // [128][32][32]
    const float* __restrict__ w,      // [128][1152]
    float* __restrict__ planes,       // [36][PSTR_] payload [1024][128] oc-minor
    int reps)
{
    __shared__ __align__(16) float Wb[32][132];  // [tap][oc], pad 132
    __shared__ __align__(16) float xs[32][64];   // [tap][l-local]

    const int t   = threadIdx.x;
    const int l0  = blockIdx.x * 64;
    const int j   = blockIdx.y;
    const int d0  = j * 32;
    const int oh0 = l0 >> 5;

    for (int rep = 0; rep < reps; ++rep) {
        // ---- stage W chunk (16 KB): 4 float4 global loads per thread ----
        float4 wld[4];
        int    wo[4], wk[4];
#pragma unroll
        for (int it = 0; it < 4; it++) {
            const int f4 = it * 256 + t;
            wo[it]  = f4 >> 3;
            wk[it]  = (f4 & 7) * 4;
            wld[it] = *(const float4*)(w + wo[it] * CKK_ + d0 + wk[it]);
        }

        // ---- stage x chunk (8 KB): 8 predicated scalar loads per thread ----
        float xl[8];
        int   xk[8], xll[8];
#pragma unroll
        for (int it = 0; it < 8; it++) {
            const int e  = it * 256 + t;
            const int k  = e >> 6, ll = e & 63;
            const int d  = d0 + k;
            const int c  = d / 9, r = d - 9 * c;
            const int kh = r / 3, kw = r - 3 * kh;
            const int iy = oh0 + (ll >> 5) + kh - 1;
            const int ix = (ll & 31) + kw - 1;
            const bool ok = ((unsigned)iy < 32u) & ((unsigned)ix < 32u);
            const int idx = ok ? (c * 1024 + iy * 32 + ix) : 0;
            const float v = x[idx];
            xl[it] = ok ? v : 0.f;
            xk[it] = k; xll[it] = ll;
        }

        __syncthreads();   // protect LDS from previous rep's readers
#pragma unroll
        for (int it = 0; it < 4; it++) {
            Wb[wk[it] + 0][wo[it]] = wld[it].x;
            Wb[wk[it] + 1][wo[it]] = wld[it].y;
            Wb[wk[it] + 2][wo[it]] = wld[it].z;
            Wb[wk[it] + 3][wo[it]] = wld[it].w;
        }
#pragma unroll
        for (int it = 0; it < 8; it++)
            xs[xk[it]][xll[it]] = xl[it];
        __syncthreads();

        // ---- compute: 4 oc x 8 px per thread, 1024 FMA ----
        const int oc0 = (t & 31) * 4;
        const int ll0 = (t >> 5) * 8;
        float acc[4][8];
#pragma unroll
        for (int r = 0; r < 4; r++)
#pragma unroll
            for (int i = 0; i < 8; i++) acc[r][i] = 0.f;

#pragma unroll
        for (int k = 0; k < 32; k++) {
            const float4 wv = *(const float4*)&Wb[k][oc0];
            const float4 xa = *(const float4*)&xs[k][ll0];
            const float4 xb = *(const float4*)&xs[k][ll0 + 4];
            acc[0][0] = fmaf(wv.x, xa.x, acc[0][0]);
            acc[0][1] = fmaf(wv.x, xa.y, acc[0][1]);
            acc[0][2] = fmaf(wv.x, xa.z, acc[0][2]);
            acc[0][3] = fmaf(wv.x, xa.w, acc[0][3]);
            acc[0][4] = fmaf(wv.x, xb.x, acc[0][4]);
            acc[0][5] = fmaf(wv.x, xb.y, acc[0][5]);
            acc[0][6] = fmaf(wv.x, xb.z, acc[0][6]);
            acc[0][7] = fmaf(wv.x, xb.w, acc[0][7]);
            acc[1][0] = fmaf(wv.y, xa.x, acc[1][0]);
            acc[1][1] = fmaf(wv.y, xa.y, acc[1][1]);
            acc[1][2] = fmaf(wv.y, xa.z, acc[1][2]);
            acc[1][3] = fmaf(wv.y, xa.w, acc[1][3]);
            acc[1][4] = fmaf(wv.y, xb.x, acc[1][4]);
            acc[1][5] = fmaf(wv.y, xb.y, acc[1][5]);
            acc[1][6] = fmaf(wv.y, xb.z, acc[1][6]);
            acc[1][7] = fmaf(wv.y, xb.w, acc[1][7]);
            acc[2][0] = fmaf(wv.z, xa.x, acc[2][0]);
            acc[2][1] = fmaf(wv.z, xa.y, acc[2][1]);
            acc[2][2] = fmaf(wv.z, xa.z, acc[2][2]);
            acc[2][3] = fmaf(wv.z, xa.w, acc[2][3]);
            acc[2][4] = fmaf(wv.z, xb.x, acc[2][4]);
            acc[2][5] = fmaf(wv.z, xb.y, acc[2][5]);
            acc[2][6] = fmaf(wv.z, xb.z, acc[2][6]);
            acc[2][7] = fmaf(wv.z, xb.w, acc[2][7]);
            acc[3][0] = fmaf(wv.w, xa.x, acc[3][0]);
            acc[3][1] = fmaf(wv.w, xa.y, acc[3][1]);
            acc[3][2] = fmaf(wv.w, xa.z, acc[3][2]);
            acc[3][3] = fmaf(wv.w, xa.w, acc[3][3]);
            acc[3][4] = fmaf(wv.w, xb.x, acc[3][4]);
            acc[3][5] = fmaf(wv.w, xb.y, acc[3][5]);
            acc[3][6] = fmaf(wv.w, xb.z, acc[3][6]);
            acc[3][7] = fmaf(wv.w, xb.w, acc[3][7]);
        }

        float* dst = planes + (size_t)j * PSTR_ + (size_t)l0 * 128;
#pragma unroll
        for (int i = 0; i < 8; i++)
            *(float4*)(dst + (ll0 + i) * 128 + oc0) =
                make_float4(acc[0][i], acc[1][i], acc[2][i], acc[3][i]);

        __asm__ volatile("" ::: "memory");   // defeat cross-rep CSE
    }
}

// Fused minmax+quant, one block per pixel.
__global__ __launch_bounds__(256) void fused_mq(
    const float* __restrict__ planes,  // [36][PSTR_]
    const float* __restrict__ bias,    // [128]
    float* __restrict__ out,           // [128][1024]
    int reps)
{
    __shared__ float part[256];
    __shared__ float mnb[128], mxb[128];
    __shared__ float s_sc, s_zp, s_iv;
    const int t  = threadIdx.x;
    const int oc = t & 127, jh = t >> 7;
    const int l  = blockIdx.x;

    for (int rep = 0; rep < reps; ++rep) {
        const float* p = planes + (size_t)(jh * 18) * PSTR_ + (size_t)l * 128 + oc;
        float v[18];
#pragma unroll
        for (int j = 0; j < 18; j++) v[j] = p[(size_t)j * PSTR_];

        float s = 0.f;
#pragma unroll
        for (int j = 0; j < 18; j++) s += v[j];
        __syncthreads();   // protect part[] from previous rep
        part[t] = s;
        __syncthreads();

        if (t < 128) {
            const float tot = part[t] + part[t + 128] + bias[t];
            mnb[t] = tot;
            mxb[t] = tot;
        }
        __syncthreads();
#pragma unroll
        for (int st = 64; st > 0; st >>= 1) {
            if (t < st) {
                mnb[t] = fminf(mnb[t], mnb[t + st]);
                mxb[t] = fmaxf(mxb[t], mxb[t + st]);
            }
            __syncthreads();
        }
        if (t == 0) {
            const float amn = mnb[0], amx = mxb[0];
            const float sv  = (amx - amn) / QMAX_;
            float z = -amn / sv;
            z = fmaxf(z, 0.f);      // fmaxf(NaN,0)=0 matches where(isnan, 0)
            z = fminf(z, QMAX_);
            z = truncf(z);
            s_sc = sv;
            s_zp = z;
            s_iv = 1.0f / sv;
        }
        __syncthreads();

        const float sc = s_sc, zv = s_zp, iv = s_iv;
        float q = 0.f;
#pragma unroll
        for (int j = 0; j < 18; j++) {
            float qn = rintf(v[j] * iv) + zv;   // rintf == round-half-even
            qn = fminf(fmaxf(qn, 0.f), QMAX_);
            q += (qn - zv) * sc;
        }
        part[t] = q;
        __syncthreads();

        if (t < 128)
            out[oc * L_ + l] = part[t] + part[t + 128];

        __asm__ volatile("" ::: "memory");   // defeat cross-rep CSE
    }
}

// ---- small-ws fallback (~520 KB): known-correct two-pass, no reps ----
template <bool QUANT>
__global__ __launch_bounds__(256) void cas_direct(
    const float* __restrict__ x, const float* __restrict__ w,
    float* __restrict__ out, const float* __restrict__ scale,
    const float* __restrict__ zp, const float* __restrict__ inv)
{
    const int t = threadIdx.x;
    const int ocBase = blockIdx.x * 16;
    const int l = blockIdx.y * 256 + t;
    const int oh = l >> 5, ow = l & 31;

    float sc = 0.f, zv = 0.f, iv = 0.f;
    if (QUANT) { sc = scale[l]; zv = zp[l]; iv = inv[l]; }

    float acc[16];
#pragma unroll
    for (int oc = 0; oc < 16; oc++) acc[oc] = 0.f;

    for (int j = 0; j < NCH; j++) {
        const int d0 = j * 32;
        float xv[32];
#pragma unroll
        for (int dd = 0; dd < 32; dd++) {
            const int d = d0 + dd, c = d / 9, r = d - 9 * c;
            const int kh = r / 3, kw = r - 3 * kh;
            const int off = c * 1024 + (kh - 1) * 32 + (kw - 1);
            const bool ok = ((unsigned)(oh + kh - 1) < 32u) &
                            ((unsigned)(ow + kw - 1) < 32u);
            const int idx = ok ? (off + l) : 0;
            const float vv = x[idx];
            xv[dd] = ok ? vv : 0.f;
        }
#pragma unroll
        for (int oc = 0; oc < 16; oc++) {
            const float4* wp = (const float4*)(w + (ocBase + oc) * CKK_ + d0);
            float pa = 0.f, pb = 0.f;
#pragma unroll
            for (int k4 = 0; k4 < 8; k4++) {
                const float4 wv = wp[k4];
                float& pr = (k4 < 4) ? pa : pb;
                pr = fmaf(wv.x, xv[4 * k4 + 0], pr);
                pr = fmaf(wv.y, xv[4 * k4 + 1], pr);
                pr = fmaf(wv.z, xv[4 * k4 + 2], pr);
                pr = fmaf(wv.w, xv[4 * k4 + 3], pr);
            }
            const float s2 = pa + pb;
            if (QUANT) {
                float qn = rintf(s2 * iv) + zv;
                qn = fminf(fmaxf(qn, 0.f), QMAX_);
                acc[oc] += (qn - zv) * sc;
            } else {
                acc[oc] += s2;
            }
        }
    }
#pragma unroll
    for (int oc = 0; oc < 16; oc++)
        out[(ocBase + oc) * L_ + l] = acc[oc];
}

__global__ __launch_bounds__(256) void minmax_conv(
    const float* __restrict__ conv, const float* __restrict__ bias,
    float* __restrict__ scale, float* __restrict__ zp, float* __restrict__ inv)
{
    __shared__ float smn[16][17], smx[16][17];
    const int t = threadIdx.x, li = t & 15, g = t >> 4;
    const int l = blockIdx.x * 16 + li;
    float mn = INFINITY, mx = -INFINITY;
#pragma unroll
    for (int i = 0; i < 8; i++) {
        const int oc = g * 8 + i;
        const float v = conv[oc * L_ + l] + bias[oc];
        mn = fminf(mn, v); mx = fmaxf(mx, v);
    }
    smn[g][li] = mn; smx[g][li] = mx;
    __syncthreads();
    if (t < 16) {
        const int l2 = blockIdx.x * 16 + t;
        float amn = smn[0][t], amx = smx[0][t];
#pragma unroll
        for (int g2 = 1; g2 < 16; g2++) {
            amn = fminf(amn, smn[g2][t]); amx = fmaxf(amx, smx[g2][t]);
        }
        const float s = (amx - amn) / QMAX_;
        float z = -amn / s;
        z = fminf(fmaxf(z, 0.f), QMAX_);
        z = truncf(z);
        scale[l2] = s; zp[l2] = z; inv[l2] = 1.0f / s;
    }
}

extern "C" void kernel_launch(void* const* d_in, const int* in_sizes, int n_in,
                              void* d_out, int out_size, void* d_ws, size_t ws_size,
                              hipStream_t stream) {
    const float* x    = (const float*)d_in[0];  // 128*32*32
    const float* w    = (const float*)d_in[1];  // 128*1152
    const float* bias = (const float*)d_in[2];  // 128
    float* out = (float*)d_out;                 // 128*1024
    float* ws  = (float*)d_ws;

    const size_t main_need = (size_t)NCH * PSTR_ * 4;
    if (ws_size >= main_need) {
        float* planes = ws;                     // 36 * PSTR_, [j][l][oc]
        const int REP = 8;                      // DIAGNOSTIC round; revert to 1
        gemm_chunks<<<dim3(16, NCH), 256, 0, stream>>>(x, w, planes, REP);
        fused_mq<<<1024, 256, 0, stream>>>(planes, bias, out, REP);
    } else {
        float* conv  = ws;
        float* scale = conv + 131072;
        float* zpv   = scale + 1024;
        float* inv   = zpv + 1024;
        cas_direct<false><<<dim3(8, 4), 256, 0, stream>>>(x, w, conv, nullptr, nullptr, nullptr);
        minmax_conv<<<64, 256, 0, stream>>>(conv, bias, scale, zpv, inv);
        cas_direct<true><<<dim3(8, 4), 256, 0, stream>>>(x, w, out, scale, zpv, inv);
    }
}

// Round 10
// 79.379 us; speedup vs baseline: 1.4893x; 1.4893x over previous
//
#include <hip/hip_runtime.h>

// casConv2d: B=1, C=128, H=W=32, OC=128, K=3, pad=1, stride=1.
// L = 1024, CKK = 1152 = 36 exact 32-tap chunks (reference front-pad chunk == 0).
//
// Round-10. R9's REP=8 diagnostic measured the split: gemm ~6.1 us/pass,
// consumer (fused_mq) ~20 us cold / ~0.1 us warm. The cold cost is the
// consumer epilogue: out[oc][l] stores with lanes spanning oc = 128 scattered
// 4B touches per wave, each 64B line co-owned by 16 blocks -> cross-XCD
// partial-line merges (R1's atomic disease, hidden in the epilogue since R5).
// Fix: split consumer into
//   K1 minmax_k  (1024 blocks): plane sums -> scale/zp/inv. XCD-swizzled so
//       block b reads pixels whose K2 reader shares b%8 (L2 locality hint).
//   K2 quant_k   (512 blocks): 16oc x 16px tile, LDS transpose, FULL-LINE
//       single-writer out stores. Plane reads are L2-warm behind K1.
#define L_     1024
#define CKK_   1152
#define QMAX_  255.0f
#define NCH    36
#define PSTR_  (131072 + 64)  // plane stride in floats (R8 pad kept)

// grid = (16 l-tiles of 64 px, 36 chunks) = 576 blocks, 256 threads.
// Unchanged from R8 (measured 6.1 us/pass, VALUBusy 36%).
__global__ __launch_bounds__(256) void gemm_chunks(
    const float* __restrict__ x,      // [128][32][32]
    const float* __restrict__ w,      // [128][1152]
    float* __restrict__ planes)       // [36][PSTR_] payload [1024][128] oc-minor
{
    __shared__ __align__(16) float Wb[32][132];  // [tap][oc], pad 132
    __shared__ __align__(16) float xs[32][64];   // [tap][l-local]

    const int t   = threadIdx.x;
    const int l0  = blockIdx.x * 64;
    const int j   = blockIdx.y;
    const int d0  = j * 32;
    const int oh0 = l0 >> 5;

    // ---- stage W chunk (16 KB): 4 float4 global loads per thread ----
    float4 wld[4];
    int    wo[4], wk[4];
#pragma unroll
    for (int it = 0; it < 4; it++) {
        const int f4 = it * 256 + t;
        wo[it]  = f4 >> 3;
        wk[it]  = (f4 & 7) * 4;
        wld[it] = *(const float4*)(w + wo[it] * CKK_ + d0 + wk[it]);
    }

    // ---- stage x chunk (8 KB): 8 predicated scalar loads per thread ----
    float xl[8];
    int   xk[8], xll[8];
#pragma unroll
    for (int it = 0; it < 8; it++) {
        const int e  = it * 256 + t;
        const int k  = e >> 6, ll = e & 63;
        const int d  = d0 + k;
        const int c  = d / 9, r = d - 9 * c;
        const int kh = r / 3, kw = r - 3 * kh;
        const int iy = oh0 + (ll >> 5) + kh - 1;
        const int ix = (ll & 31) + kw - 1;
        const bool ok = ((unsigned)iy < 32u) & ((unsigned)ix < 32u);
        const int idx = ok ? (c * 1024 + iy * 32 + ix) : 0;
        const float v = x[idx];
        xl[it] = ok ? v : 0.f;
        xk[it] = k; xll[it] = ll;
    }

#pragma unroll
    for (int it = 0; it < 4; it++) {
        Wb[wk[it] + 0][wo[it]] = wld[it].x;
        Wb[wk[it] + 1][wo[it]] = wld[it].y;
        Wb[wk[it] + 2][wo[it]] = wld[it].z;
        Wb[wk[it] + 3][wo[it]] = wld[it].w;
    }
#pragma unroll
    for (int it = 0; it < 8; it++)
        xs[xk[it]][xll[it]] = xl[it];
    __syncthreads();

    // ---- compute: 4 oc x 8 px per thread, 1024 FMA ----
    const int oc0 = (t & 31) * 4;
    const int ll0 = (t >> 5) * 8;
    float acc[4][8];
#pragma unroll
    for (int r = 0; r < 4; r++)
#pragma unroll
        for (int i = 0; i < 8; i++) acc[r][i] = 0.f;

#pragma unroll
    for (int k = 0; k < 32; k++) {
        const float4 wv = *(const float4*)&Wb[k][oc0];
        const float4 xa = *(const float4*)&xs[k][ll0];
        const float4 xb = *(const float4*)&xs[k][ll0 + 4];
        acc[0][0] = fmaf(wv.x, xa.x, acc[0][0]);
        acc[0][1] = fmaf(wv.x, xa.y, acc[0][1]);
        acc[0][2] = fmaf(wv.x, xa.z, acc[0][2]);
        acc[0][3] = fmaf(wv.x, xa.w, acc[0][3]);
        acc[0][4] = fmaf(wv.x, xb.x, acc[0][4]);
        acc[0][5] = fmaf(wv.x, xb.y, acc[0][5]);
        acc[0][6] = fmaf(wv.x, xb.z, acc[0][6]);
        acc[0][7] = fmaf(wv.x, xb.w, acc[0][7]);
        acc[1][0] = fmaf(wv.y, xa.x, acc[1][0]);
        acc[1][1] = fmaf(wv.y, xa.y, acc[1][1]);
        acc[1][2] = fmaf(wv.y, xa.z, acc[1][2]);
        acc[1][3] = fmaf(wv.y, xa.w, acc[1][3]);
        acc[1][4] = fmaf(wv.y, xb.x, acc[1][4]);
        acc[1][5] = fmaf(wv.y, xb.y, acc[1][5]);
        acc[1][6] = fmaf(wv.y, xb.z, acc[1][6]);
        acc[1][7] = fmaf(wv.y, xb.w, acc[1][7]);
        acc[2][0] = fmaf(wv.z, xa.x, acc[2][0]);
        acc[2][1] = fmaf(wv.z, xa.y, acc[2][1]);
        acc[2][2] = fmaf(wv.z, xa.z, acc[2][2]);
        acc[2][3] = fmaf(wv.z, xa.w, acc[2][3]);
        acc[2][4] = fmaf(wv.z, xb.x, acc[2][4]);
        acc[2][5] = fmaf(wv.z, xb.y, acc[2][5]);
        acc[2][6] = fmaf(wv.z, xb.z, acc[2][6]);
        acc[2][7] = fmaf(wv.z, xb.w, acc[2][7]);
        acc[3][0] = fmaf(wv.w, xa.x, acc[3][0]);
        acc[3][1] = fmaf(wv.w, xa.y, acc[3][1]);
        acc[3][2] = fmaf(wv.w, xa.z, acc[3][2]);
        acc[3][3] = fmaf(wv.w, xa.w, acc[3][3]);
        acc[3][4] = fmaf(wv.w, xb.x, acc[3][4]);
        acc[3][5] = fmaf(wv.w, xb.y, acc[3][5]);
        acc[3][6] = fmaf(wv.w, xb.z, acc[3][6]);
        acc[3][7] = fmaf(wv.w, xb.w, acc[3][7]);
    }

    float* dst = planes + (size_t)j * PSTR_ + (size_t)l0 * 128;
#pragma unroll
    for (int i = 0; i < 8; i++)
        *(float4*)(dst + (ll0 + i) * 128 + oc0) =
            make_float4(acc[0][i], acc[1][i], acc[2][i], acc[3][i]);
}

// K1: per-pixel scale/zp/inv. 1024 blocks, one pixel each (R8's proven
// reduction). Pixel assignment swizzled so this block's XCD (b%8) matches
// the K2 reader's XCD ((l/16)%8) — L2-locality heuristic, correctness-free.
__global__ __launch_bounds__(256) void minmax_k(
    const float* __restrict__ planes,  // [36][PSTR_]
    const float* __restrict__ bias,    // [128]
    float* __restrict__ scale, float* __restrict__ zp, float* __restrict__ inv)
{
    __shared__ float part[256];
    __shared__ float mnb[128], mxb[128];
    const int t  = threadIdx.x;
    const int oc = t & 127, jh = t >> 7;
    const int b  = blockIdx.x;
    const int xx = b & 7, rr = b >> 3;                 // rr in 0..127
    const int l  = (xx + 8 * (rr & 7)) * 16 + (rr >> 3);  // (l/16)%8 == b%8

    const float* p = planes + (size_t)(jh * 18) * PSTR_ + (size_t)l * 128 + oc;
    float s = 0.f;
#pragma unroll
    for (int j = 0; j < 18; j++) s += p[(size_t)j * PSTR_];
    part[t] = s;
    __syncthreads();

    if (t < 128) {
        const float tot = part[t] + part[t + 128] + bias[t];
        mnb[t] = tot;
        mxb[t] = tot;
    }
    __syncthreads();
#pragma unroll
    for (int st = 64; st > 0; st >>= 1) {
        if (t < st) {
            mnb[t] = fminf(mnb[t], mnb[t + st]);
            mxb[t] = fmaxf(mxb[t], mxb[t + st]);
        }
        __syncthreads();
    }
    if (t == 0) {
        const float amn = mnb[0], amx = mxb[0];
        const float sv  = (amx - amn) / QMAX_;
        float z = -amn / sv;
        z = fmaxf(z, 0.f);          // fmaxf(NaN,0)=0 matches where(isnan, 0)
        z = fminf(z, QMAX_);
        z = truncf(z);
        scale[l] = sv;
        zp[l]    = z;
        inv[l]   = 1.0f / sv;
    }
}

// K2: quant + reduce over chunks. 512 blocks x 256 thr; tile = 16 oc x 16 px.
// Plane reads L2-warm (K1 just streamed them). LDS transpose so out stores
// are FULL 64B lines, each line written by exactly one block.
__global__ __launch_bounds__(256) void quant_k(
    const float* __restrict__ planes,
    const float* __restrict__ scale, const float* __restrict__ zp,
    const float* __restrict__ inv, float* __restrict__ out)
{
    __shared__ float otile[16][17];   // [oc-local][l-local], padded
    const int t   = threadIdx.x;
    const int oi  = t & 15, li = t >> 4;
    const int ocg = blockIdx.x & 7, lg = blockIdx.x >> 3;
    const int oc  = ocg * 16 + oi, l = lg * 16 + li;

    const float sv = scale[l], zv = zp[l], iv = inv[l];
    const float* p = planes + (size_t)l * 128 + oc;

    float qa = 0.f, qb = 0.f;          // two chains for ILP
#pragma unroll
    for (int j = 0; j < NCH; j += 2) {
        const float a0 = p[(size_t)j * PSTR_];
        const float a1 = p[(size_t)(j + 1) * PSTR_];
        float q0 = rintf(a0 * iv) + zv;            // rintf == round-half-even
        q0 = fminf(fmaxf(q0, 0.f), QMAX_);
        qa += (q0 - zv) * sv;
        float q1 = rintf(a1 * iv) + zv;
        q1 = fminf(fmaxf(q1, 0.f), QMAX_);
        qb += (q1 - zv) * sv;
    }
    otile[oi][li] = qa + qb;
    __syncthreads();

    // full-line stores: 16 lanes cover 16 consecutive l (64 B) per oc row.
    const int ocs = t >> 4, ls = t & 15;
    out[(ocg * 16 + ocs) * L_ + lg * 16 + ls] = otile[ocs][ls];
}

// ---- small-ws fallback (~520 KB): known-correct two-pass ----
template <bool QUANT>
__global__ __launch_bounds__(256) void cas_direct(
    const float* __restrict__ x, const float* __restrict__ w,
    float* __restrict__ out, const float* __restrict__ scale,
    const float* __restrict__ zp, const float* __restrict__ inv)
{
    const int t = threadIdx.x;
    const int ocBase = blockIdx.x * 16;
    const int l = blockIdx.y * 256 + t;
    const int oh = l >> 5, ow = l & 31;

    float sc = 0.f, zv = 0.f, iv = 0.f;
    if (QUANT) { sc = scale[l]; zv = zp[l]; iv = inv[l]; }

    float acc[16];
#pragma unroll
    for (int oc = 0; oc < 16; oc++) acc[oc] = 0.f;

    for (int j = 0; j < NCH; j++) {
        const int d0 = j * 32;
        float xv[32];
#pragma unroll
        for (int dd = 0; dd < 32; dd++) {
            const int d = d0 + dd, c = d / 9, r = d - 9 * c;
            const int kh = r / 3, kw = r - 3 * kh;
            const int off = c * 1024 + (kh - 1) * 32 + (kw - 1);
            const bool ok = ((unsigned)(oh + kh - 1) < 32u) &
                            ((unsigned)(ow + kw - 1) < 32u);
            const int idx = ok ? (off + l) : 0;
            const float vv = x[idx];
            xv[dd] = ok ? vv : 0.f;
        }
#pragma unroll
        for (int oc = 0; oc < 16; oc++) {
            const float4* wp = (const float4*)(w + (ocBase + oc) * CKK_ + d0);
            float pa = 0.f, pb = 0.f;
#pragma unroll
            for (int k4 = 0; k4 < 8; k4++) {
                const float4 wv = wp[k4];
                float& pr = (k4 < 4) ? pa : pb;
                pr = fmaf(wv.x, xv[4 * k4 + 0], pr);
                pr = fmaf(wv.y, xv[4 * k4 + 1], pr);
                pr = fmaf(wv.z, xv[4 * k4 + 2], pr);
                pr = fmaf(wv.w, xv[4 * k4 + 3], pr);
            }
            const float s2 = pa + pb;
            if (QUANT) {
                float qn = rintf(s2 * iv) + zv;
                qn = fminf(fmaxf(qn, 0.f), QMAX_);
                acc[oc] += (qn - zv) * sc;
            } else {
                acc[oc] += s2;
            }
        }
    }
#pragma unroll
    for (int oc = 0; oc < 16; oc++)
        out[(ocBase + oc) * L_ + l] = acc[oc];
}

__global__ __launch_bounds__(256) void minmax_conv(
    const float* __restrict__ conv, const float* __restrict__ bias,
    float* __restrict__ scale, float* __restrict__ zp, float* __restrict__ inv)
{
    __shared__ float smn[16][17], smx[16][17];
    const int t = threadIdx.x, li = t & 15, g = t >> 4;
    const int l = blockIdx.x * 16 + li;
    float mn = INFINITY, mx = -INFINITY;
#pragma unroll
    for (int i = 0; i < 8; i++) {
        const int oc = g * 8 + i;
        const float v = conv[oc * L_ + l] + bias[oc];
        mn = fminf(mn, v); mx = fmaxf(mx, v);
    }
    smn[g][li] = mn; smx[g][li] = mx;
    __syncthreads();
    if (t < 16) {
        const int l2 = blockIdx.x * 16 + t;
        float amn = smn[0][t], amx = smx[0][t];
#pragma unroll
        for (int g2 = 1; g2 < 16; g2++) {
            amn = fminf(amn, smn[g2][t]); amx = fmaxf(amx, smx[g2][t]);
        }
        const float s = (amx - amn) / QMAX_;
        float z = -amn / s;
        z = fminf(fmaxf(z, 0.f), QMAX_);
        z = truncf(z);
        scale[l2] = s; zp[l2] = z; inv[l2] = 1.0f / s;
    }
}

extern "C" void kernel_launch(void* const* d_in, const int* in_sizes, int n_in,
                              void* d_out, int out_size, void* d_ws, size_t ws_size,
                              hipStream_t stream) {
    const float* x    = (const float*)d_in[0];  // 128*32*32
    const float* w    = (const float*)d_in[1];  // 128*1152
    const float* bias = (const float*)d_in[2];  // 128
    float* out = (float*)d_out;                 // 128*1024
    float* ws  = (float*)d_ws;

    const size_t main_need = ((size_t)NCH * PSTR_ + 3 * 1024) * 4;
    if (ws_size >= main_need) {
        float* planes = ws;                     // 36 * PSTR_, [j][l][oc]
        float* scale  = planes + (size_t)NCH * PSTR_;
        float* zpv    = scale + 1024;
        float* inv    = zpv + 1024;

        gemm_chunks<<<dim3(16, NCH), 256, 0, stream>>>(x, w, planes);
        minmax_k<<<1024, 256, 0, stream>>>(planes, bias, scale, zpv, inv);
        quant_k<<<512, 256, 0, stream>>>(planes, scale, zpv, inv, out);
    } else {
        float* conv  = ws;
        float* scale = conv + 131072;
        float* zpv   = scale + 1024;
        float* inv   = zpv + 1024;
        cas_direct<false><<<dim3(8, 4), 256, 0, stream>>>(x, w, conv, nullptr, nullptr, nullptr);
        minmax_conv<<<64, 256, 0, stream>>>(conv, bias, scale, zpv, inv);
        cas_direct<true><<<dim3(8, 4), 256, 0, stream>>>(x, w, out, scale, zpv, inv);
    }
}

// Round 11
// 75.435 us; speedup vs baseline: 1.5671x; 1.0523x over previous
//
#include <hip/hip_runtime.h>

// casConv2d: B=1, C=128, H=W=32, OC=128, K=3, pad=1, stride=1.
// L = 1024, CKK = 1152 = 36 exact 32-tap chunks (reference front-pad chunk == 0).
//
// Round-11. R9 measured: consumer ~20us cold / ~0.1us warm; R10's split
// (reading planes twice) regressed, pinning consumer cost to COLD PLANE READS
// (~2 TB/s effective). Diagnosis: in [j][l][oc] layout each consumer block's
// 18 KB footprint is 36 scattered 512B granules (512 KB apart) -> ~37k
// scattered small requests chip-wide, a slow DRAM/LLC access class. Fix
// (single variable vs R8): plane layout -> [l][j][oc] (pixel-major). Each
// consumer block now reads ONE contiguous 18 KB stretch; gemm stores become
// 64 single-writer full-line 512B granules at 18 KB stride.
#define L_     1024
#define CKK_   1152
#define QMAX_  255.0f
#define NCH    36
#define PST_   4608           // pixel stride in floats: 36 chunks * 128 oc (18 KB)

// grid = (16 l-tiles of 64 px, 36 chunks) = 576 blocks, 256 threads.
// Same compute as R8 (measured 6.1 us/pass); only the store indexing changed.
__global__ __launch_bounds__(256) void gemm_chunks(
    const float* __restrict__ x,      // [128][32][32]
    const float* __restrict__ w,      // [128][1152]
    float* __restrict__ planes)       // [1024][36][128]  (pixel-major)
{
    __shared__ __align__(16) float Wb[32][132];  // [tap][oc], pad 132
    __shared__ __align__(16) float xs[32][64];   // [tap][l-local]

    const int t   = threadIdx.x;
    const int l0  = blockIdx.x * 64;
    const int j   = blockIdx.y;
    const int d0  = j * 32;
    const int oh0 = l0 >> 5;

    // ---- stage W chunk (16 KB): 4 float4 global loads per thread ----
    float4 wld[4];
    int    wo[4], wk[4];
#pragma unroll
    for (int it = 0; it < 4; it++) {
        const int f4 = it * 256 + t;
        wo[it]  = f4 >> 3;
        wk[it]  = (f4 & 7) * 4;
        wld[it] = *(const float4*)(w + wo[it] * CKK_ + d0 + wk[it]);
    }

    // ---- stage x chunk (8 KB): 8 predicated scalar loads per thread ----
    float xl[8];
    int   xk[8], xll[8];
#pragma unroll
    for (int it = 0; it < 8; it++) {
        const int e  = it * 256 + t;
        const int k  = e >> 6, ll = e & 63;
        const int d  = d0 + k;
        const int c  = d / 9, r = d - 9 * c;
        const int kh = r / 3, kw = r - 3 * kh;
        const int iy = oh0 + (ll >> 5) + kh - 1;
        const int ix = (ll & 31) + kw - 1;
        const bool ok = ((unsigned)iy < 32u) & ((unsigned)ix < 32u);
        const int idx = ok ? (c * 1024 + iy * 32 + ix) : 0;
        const float v = x[idx];
        xl[it] = ok ? v : 0.f;
        xk[it] = k; xll[it] = ll;
    }

#pragma unroll
    for (int it = 0; it < 4; it++) {
        Wb[wk[it] + 0][wo[it]] = wld[it].x;
        Wb[wk[it] + 1][wo[it]] = wld[it].y;
        Wb[wk[it] + 2][wo[it]] = wld[it].z;
        Wb[wk[it] + 3][wo[it]] = wld[it].w;
    }
#pragma unroll
    for (int it = 0; it < 8; it++)
        xs[xk[it]][xll[it]] = xl[it];
    __syncthreads();

    // ---- compute: 4 oc x 8 px per thread, 1024 FMA ----
    const int oc0 = (t & 31) * 4;
    const int ll0 = (t >> 5) * 8;
    float acc[4][8];
#pragma unroll
    for (int r = 0; r < 4; r++)
#pragma unroll
        for (int i = 0; i < 8; i++) acc[r][i] = 0.f;

#pragma unroll
    for (int k = 0; k < 32; k++) {
        const float4 wv = *(const float4*)&Wb[k][oc0];
        const float4 xa = *(const float4*)&xs[k][ll0];
        const float4 xb = *(const float4*)&xs[k][ll0 + 4];
        acc[0][0] = fmaf(wv.x, xa.x, acc[0][0]);
        acc[0][1] = fmaf(wv.x, xa.y, acc[0][1]);
        acc[0][2] = fmaf(wv.x, xa.z, acc[0][2]);
        acc[0][3] = fmaf(wv.x, xa.w, acc[0][3]);
        acc[0][4] = fmaf(wv.x, xb.x, acc[0][4]);
        acc[0][5] = fmaf(wv.x, xb.y, acc[0][5]);
        acc[0][6] = fmaf(wv.x, xb.z, acc[0][6]);
        acc[0][7] = fmaf(wv.x, xb.w, acc[0][7]);
        acc[1][0] = fmaf(wv.y, xa.x, acc[1][0]);
        acc[1][1] = fmaf(wv.y, xa.y, acc[1][1]);
        acc[1][2] = fmaf(wv.y, xa.z, acc[1][2]);
        acc[1][3] = fmaf(wv.y, xa.w, acc[1][3]);
        acc[1][4] = fmaf(wv.y, xb.x, acc[1][4]);
        acc[1][5] = fmaf(wv.y, xb.y, acc[1][5]);
        acc[1][6] = fmaf(wv.y, xb.z, acc[1][6]);
        acc[1][7] = fmaf(wv.y, xb.w, acc[1][7]);
        acc[2][0] = fmaf(wv.z, xa.x, acc[2][0]);
        acc[2][1] = fmaf(wv.z, xa.y, acc[2][1]);
        acc[2][2] = fmaf(wv.z, xa.z, acc[2][2]);
        acc[2][3] = fmaf(wv.z, xa.w, acc[2][3]);
        acc[2][4] = fmaf(wv.z, xb.x, acc[2][4]);
        acc[2][5] = fmaf(wv.z, xb.y, acc[2][5]);
        acc[2][6] = fmaf(wv.z, xb.z, acc[2][6]);
        acc[2][7] = fmaf(wv.z, xb.w, acc[2][7]);
        acc[3][0] = fmaf(wv.w, xa.x, acc[3][0]);
        acc[3][1] = fmaf(wv.w, xa.y, acc[3][1]);
        acc[3][2] = fmaf(wv.w, xa.z, acc[3][2]);
        acc[3][3] = fmaf(wv.w, xa.w, acc[3][3]);
        acc[3][4] = fmaf(wv.w, xb.x, acc[3][4]);
        acc[3][5] = fmaf(wv.w, xb.y, acc[3][5]);
        acc[3][6] = fmaf(wv.w, xb.z, acc[3][6]);
        acc[3][7] = fmaf(wv.w, xb.w, acc[3][7]);
    }

    // Stores: for each px row i, a half-wave writes one full 512 B granule
    // planes[l][j][0..128] — single writer, full lines, 18 KB stride.
#pragma unroll
    for (int i = 0; i < 8; i++) {
        float* dst = planes + (size_t)(l0 + ll0 + i) * PST_ + (size_t)j * 128;
        *(float4*)(dst + oc0) =
            make_float4(acc[0][i], acc[1][i], acc[2][i], acc[3][i]);
    }
}

// Fused minmax+quant (R8 structure): one block per pixel; block reads ONE
// contiguous 18 KB stretch planes[l][*][*]; 18 values/thread in VGPRs.
__global__ __launch_bounds__(256) void fused_mq(
    const float* __restrict__ planes,  // [1024][36][128]
    const float* __restrict__ bias,    // [128]
    float* __restrict__ out)           // [128][1024]
{
    __shared__ float part[256];
    __shared__ float mnb[128], mxb[128];
    __shared__ float s_sc, s_zp, s_iv;
    const int t  = threadIdx.x;
    const int oc = t & 127, jh = t >> 7;
    const int l  = blockIdx.x;

    // contiguous: half-group jh covers planes[l][jh*18 .. jh*18+18][*] (9 KB)
    const float* p = planes + (size_t)l * PST_ + (size_t)(jh * 18) * 128 + oc;
    float v[18];
#pragma unroll
    for (int j = 0; j < 18; j++) v[j] = p[j * 128];

    float s = 0.f;
#pragma unroll
    for (int j = 0; j < 18; j++) s += v[j];
    part[t] = s;
    __syncthreads();

    if (t < 128) {
        const float tot = part[t] + part[t + 128] + bias[t];
        mnb[t] = tot;
        mxb[t] = tot;
    }
    __syncthreads();
#pragma unroll
    for (int st = 64; st > 0; st >>= 1) {
        if (t < st) {
            mnb[t] = fminf(mnb[t], mnb[t + st]);
            mxb[t] = fmaxf(mxb[t], mxb[t + st]);
        }
        __syncthreads();
    }
    if (t == 0) {
        const float amn = mnb[0], amx = mxb[0];
        const float sv  = (amx - amn) / QMAX_;
        float z = -amn / sv;
        z = fmaxf(z, 0.f);          // fmaxf(NaN,0)=0 matches where(isnan, 0)
        z = fminf(z, QMAX_);
        z = truncf(z);
        s_sc = sv;
        s_zp = z;
        s_iv = 1.0f / sv;
    }
    __syncthreads();

    const float sc = s_sc, zv = s_zp, iv = s_iv;
    float q = 0.f;
#pragma unroll
    for (int j = 0; j < 18; j++) {
        float qn = rintf(v[j] * iv) + zv;   // rintf == round-half-even
        qn = fminf(fmaxf(qn, 0.f), QMAX_);
        q += (qn - zv) * sc;
    }
    part[t] = q;
    __syncthreads();

    if (t < 128)
        out[oc * L_ + l] = part[t] + part[t + 128];
}

// ---- small-ws fallback (~520 KB): known-correct two-pass ----
template <bool QUANT>
__global__ __launch_bounds__(256) void cas_direct(
    const float* __restrict__ x, const float* __restrict__ w,
    float* __restrict__ out, const float* __restrict__ scale,
    const float* __restrict__ zp, const float* __restrict__ inv)
{
    const int t = threadIdx.x;
    const int ocBase = blockIdx.x * 16;
    const int l = blockIdx.y * 256 + t;
    const int oh = l >> 5, ow = l & 31;

    float sc = 0.f, zv = 0.f, iv = 0.f;
    if (QUANT) { sc = scale[l]; zv = zp[l]; iv = inv[l]; }

    float acc[16];
#pragma unroll
    for (int oc = 0; oc < 16; oc++) acc[oc] = 0.f;

    for (int j = 0; j < NCH; j++) {
        const int d0 = j * 32;
        float xv[32];
#pragma unroll
        for (int dd = 0; dd < 32; dd++) {
            const int d = d0 + dd, c = d / 9, r = d - 9 * c;
            const int kh = r / 3, kw = r - 3 * kh;
            const int off = c * 1024 + (kh - 1) * 32 + (kw - 1);
            const bool ok = ((unsigned)(oh + kh - 1) < 32u) &
                            ((unsigned)(ow + kw - 1) < 32u);
            const int idx = ok ? (off + l) : 0;
            const float vv = x[idx];
            xv[dd] = ok ? vv : 0.f;
        }
#pragma unroll
        for (int oc = 0; oc < 16; oc++) {
            const float4* wp = (const float4*)(w + (ocBase + oc) * CKK_ + d0);
            float pa = 0.f, pb = 0.f;
#pragma unroll
            for (int k4 = 0; k4 < 8; k4++) {
                const float4 wv = wp[k4];
                float& pr = (k4 < 4) ? pa : pb;
                pr = fmaf(wv.x, xv[4 * k4 + 0], pr);
                pr = fmaf(wv.y, xv[4 * k4 + 1], pr);
                pr = fmaf(wv.z, xv[4 * k4 + 2], pr);
                pr = fmaf(wv.w, xv[4 * k4 + 3], pr);
            }
            const float s2 = pa + pb;
            if (QUANT) {
                float qn = rintf(s2 * iv) + zv;
                qn = fminf(fmaxf(qn, 0.f), QMAX_);
                acc[oc] += (qn - zv) * sc;
            } else {
                acc[oc] += s2;
            }
        }
    }
#pragma unroll
    for (int oc = 0; oc < 16; oc++)
        out[(ocBase + oc) * L_ + l] = acc[oc];
}

__global__ __launch_bounds__(256) void minmax_conv(
    const float* __restrict__ conv, const float* __restrict__ bias,
    float* __restrict__ scale, float* __restrict__ zp, float* __restrict__ inv)
{
    __shared__ float smn[16][17], smx[16][17];
    const int t = threadIdx.x, li = t & 15, g = t >> 4;
    const int l = blockIdx.x * 16 + li;
    float mn = INFINITY, mx = -INFINITY;
#pragma unroll
    for (int i = 0; i < 8; i++) {
        const int oc = g * 8 + i;
        const float v = conv[oc * L_ + l] + bias[oc];
        mn = fminf(mn, v); mx = fmaxf(mx, v);
    }
    smn[g][li] = mn; smx[g][li] = mx;
    __syncthreads();
    if (t < 16) {
        const int l2 = blockIdx.x * 16 + t;
        float amn = smn[0][t], amx = smx[0][t];
#pragma unroll
        for (int g2 = 1; g2 < 16; g2++) {
            amn = fminf(amn, smn[g2][t]); amx = fmaxf(amx, smx[g2][t]);
        }
        const float s = (amx - amn) / QMAX_;
        float z = -amn / s;
        z = fminf(fmaxf(z, 0.f), QMAX_);
        z = truncf(z);
        scale[l2] = s; zp[l2] = z; inv[l2] = 1.0f / s;
    }
}

extern "C" void kernel_launch(void* const* d_in, const int* in_sizes, int n_in,
                              void* d_out, int out_size, void* d_ws, size_t ws_size,
                              hipStream_t stream) {
    const float* x    = (const float*)d_in[0];  // 128*32*32
    const float* w    = (const float*)d_in[1];  // 128*1152
    const float* bias = (const float*)d_in[2];  // 128
    float* out = (float*)d_out;                 // 128*1024
    float* ws  = (float*)d_ws;

    const size_t main_need = (size_t)L_ * PST_ * 4;
    if (ws_size >= main_need) {
        float* planes = ws;                     // [1024][36][128], 18.9 MB
        gemm_chunks<<<dim3(16, NCH), 256, 0, stream>>>(x, w, planes);
        fused_mq<<<1024, 256, 0, stream>>>(planes, bias, out);
    } else {
        float* conv  = ws;
        float* scale = conv + 131072;
        float* zpv   = scale + 1024;
        float* inv   = zpv + 1024;
        cas_direct<false><<<dim3(8, 4), 256, 0, stream>>>(x, w, conv, nullptr, nullptr, nullptr);
        minmax_conv<<<64, 256, 0, stream>>>(conv, bias, scale, zpv, inv);
        cas_direct<true><<<dim3(8, 4), 256, 0, stream>>>(x, w, out, scale, zpv, inv);
    }
}